// Round 6
// baseline (323.678 us; speedup 1.0000x reference)
//
#include <hip/hip_runtime.h>

#define BB 8
#define DD 512
#define LL 4096
#define NH 8
#define HD 64
#define SCALE 0.125f
#define NCH2 128

typedef __attribute__((ext_vector_type(8))) short short8;
typedef __attribute__((ext_vector_type(4))) float f32x4;

// ---------- bf16 helpers (bit-level, round-to-nearest-even) ----------
static __device__ __forceinline__ float bf2f(unsigned short u) {
  union { float f; unsigned int i; } c; c.i = ((unsigned int)u) << 16; return c.f;
}
static __device__ __forceinline__ unsigned short f2bf(float f) {
  union { float f; unsigned int i; } c; c.f = f;
  unsigned int i = c.i;
  unsigned int r = (i + 0x7fffu + ((i >> 16) & 1u)) >> 16;
  return (unsigned short)r;
}

// async global->LDS, 16B per lane; lds base must be wave-uniform
static __device__ __forceinline__ void gload_lds16(const void* g, void* l) {
  __builtin_amdgcn_global_load_lds(
      (const __attribute__((address_space(1))) void*)g,
      (__attribute__((address_space(3))) void*)l, 16, 0, 0);
}

// ---------- reductions ----------
static __device__ __forceinline__ float waveSum(float v) {
#pragma unroll
  for (int o = 32; o; o >>= 1) v += __shfl_down(v, o, 64);
  return v;
}
static __device__ __forceinline__ float grp8Sum(float v) {
  v += __shfl_xor(v, 1, 8);
  v += __shfl_xor(v, 2, 8);
  v += __shfl_xor(v, 4, 8);
  return v;
}
// butterfly variants: result valid in ALL lanes
static __device__ __forceinline__ float waveAllMax(float v) {
#pragma unroll
  for (int o = 1; o < 64; o <<= 1) v = fmaxf(v, __shfl_xor(v, o, 64));
  return v;
}
static __device__ __forceinline__ float waveAllSum(float v) {
#pragma unroll
  for (int o = 1; o < 64; o <<= 1) v += __shfl_xor(v, o, 64);
  return v;
}

// ---------- fused prep: X transpose (z<BB) + 4 weight transposes (z==BB) ----------
// x-part: x[b][e][l] f32 -> xt[b][l][e] bf16, grid (64, 8, .)
// w-part: wid = x + 64*y in [0,512); wid<256: s=wid>>6 selects matrix,
//         t=wid&63: m0=(t&7)*64, d0=(t>>3)*64 (same decode as old prep_w4)
__global__ __launch_bounds__(256) void prep_all(
    const float* __restrict__ x, unsigned short* __restrict__ xt,
    const float* __restrict__ w0, const float* __restrict__ w1,
    const float* __restrict__ w2, const float* __restrict__ w3,
    unsigned short* __restrict__ o0, unsigned short* __restrict__ o1,
    unsigned short* __restrict__ o2, unsigned short* __restrict__ o3) {
  __shared__ float t[64][65];
  const int tid = threadIdx.x;
  const int r = tid >> 4;
  const int c4 = (tid & 15) * 4;
  if (blockIdx.z < BB) {
    const int b = blockIdx.z;
    const int e0 = blockIdx.y * 64;
    const int l0 = blockIdx.x * 64;
    const float* xb = x + (size_t)b * DD * LL;
#pragma unroll
    for (int p = 0; p < 4; p++) {
      const float4 v = *(const float4*)(xb + (size_t)(e0 + p * 16 + r) * LL + l0 + c4);
      *(float4*)&t[p * 16 + r][c4] = v;
    }
    __syncthreads();
#pragma unroll
    for (int p = 0; p < 4; p++) {
      const int ll = p * 16 + r;
      ushort4 o;
      o.x = f2bf(t[c4 + 0][ll]);
      o.y = f2bf(t[c4 + 1][ll]);
      o.z = f2bf(t[c4 + 2][ll]);
      o.w = f2bf(t[c4 + 3][ll]);
      *(ushort4*)(xt + ((size_t)b * LL + l0 + ll) * DD + e0 + c4) = o;
    }
  } else {
    const int wid = blockIdx.x + 64 * blockIdx.y;
    if (wid >= 256) return;
    const int s = wid >> 6;
    const int tb = wid & 63;
    const int m0 = (tb & 7) * 64;
    const int d0 = (tb >> 3) * 64;
    const float* win = (s == 0) ? w0 : (s == 1) ? w1 : (s == 2) ? w2 : w3;
    unsigned short* wout = (s == 0) ? o0 : (s == 1) ? o1 : (s == 2) ? o2 : o3;
#pragma unroll
    for (int p = 0; p < 4; p++) {
      const float4 v = *(const float4*)(win + (size_t)(d0 + p * 16 + r) * DD + m0 + c4);
      *(float4*)&t[p * 16 + r][c4] = v;
    }
    __syncthreads();
#pragma unroll
    for (int p = 0; p < 4; p++) {
      const int ll = p * 16 + r;
      ushort4 o;
      o.x = f2bf(t[c4 + 0][ll]);
      o.y = f2bf(t[c4 + 1][ll]);
      o.z = f2bf(t[c4 + 2][ll]);
      o.w = f2bf(t[c4 + 3][ll]);
      *(ushort4*)(wout + (size_t)(m0 + ll) * DD + d0 + c4) = o;
    }
  }
}

// ==================================================================
// 8-phase 256x256 MFMA GEMM core (T2+T3+T4+T5), verified R1/R4/R5.
// LINEAR block decode (R3: XCD swizzle regressed). R1 schedule (R2:
// deeper prefetch regressed). Shared by qkv and nodes kernels.
// ==================================================================
#define STAGEH(g, s)                                       \
  do {                                                     \
    gload_lds16((g) + sgoff, (s) + sloff);                 \
    gload_lds16((g) + sgoff + 32, (s) + sloff + 4096);     \
  } while (0)

#define READ_A(dst, base, ib)                                           \
  _Pragma("unroll") for (int i = 0; i < 4; i++) {                       \
    dst[i][0] = *(const short8*)((base) + ((ib) + i) * 512);            \
    dst[i][1] = *(const short8*)((base) + ((ib) + i) * 512 + 4096);     \
  }

#define READ_B(base, qn_)                                               \
  _Pragma("unroll") for (int j = 0; j < 2; j++) {                       \
    bb[j][0] = *(const short8*)((base) + (qn_) * 1024 + j * 512);       \
    bb[j][1] = *(const short8*)((base) + (qn_) * 1024 + j * 512 + 4096);\
  }

#define MFMA16(AF, IO, JO)                                                    \
  __builtin_amdgcn_s_setprio(1);                                              \
  _Pragma("unroll") for (int i = 0; i < 4; i++)                               \
  _Pragma("unroll") for (int j = 0; j < 2; j++) {                             \
    acc[(IO) + i][(JO) + j] = __builtin_amdgcn_mfma_f32_16x16x32_bf16(        \
        AF[i][0], bb[j][0], acc[(IO) + i][(JO) + j], 0, 0, 0);                \
    acc[(IO) + i][(JO) + j] = __builtin_amdgcn_mfma_f32_16x16x32_bf16(        \
        AF[i][1], bb[j][1], acc[(IO) + i][(JO) + j], 0, 0, 0);                \
  }                                                                           \
  __builtin_amdgcn_s_setprio(0);

#define PHASE_SYNC_PRE                                     \
  __builtin_amdgcn_s_barrier();                            \
  asm volatile("s_waitcnt lgkmcnt(0)" ::: "memory");       \
  __builtin_amdgcn_sched_barrier(0);

#define PHASE_SYNC_POST                                    \
  __builtin_amdgcn_sched_barrier(0);                       \
  __builtin_amdgcn_s_barrier();

// the shared K-loop body (prologue + 8 K-tiles); declares/fills acc[8][4]
#define GEMM_8PH_CORE                                                         \
  const int lane = tid & 63, w = tid >> 6;                                    \
  const int wm = w >> 2, wn = w & 3;                                          \
  const int l15 = lane & 15, lh = lane >> 4;                                  \
  const int kswz = (lh << 3) ^ ((l15 & 8) << 1);                              \
  const unsigned short* aB = sm + wm * 8192 + l15 * 32 + kswz;                \
  const unsigned short* bB = sm + 32768 + (wn >> 1) * 8192 +                  \
                             (wn & 1) * 2048 + l15 * 32 + kswz;               \
  const int srow = (w << 4) + (lane >> 2);                                    \
  const size_t sgoff = (size_t)srow * DD +                                    \
      ((size_t)(((lane & 3) << 3) ^ ((srow & 8) << 1)));                      \
  const int sloff = w * 512;                                                  \
  f32x4 acc[8][4];                                                            \
  _Pragma("unroll") for (int i = 0; i < 8; i++)                               \
  _Pragma("unroll") for (int j = 0; j < 4; j++)                               \
      acc[i][j] = (f32x4){0.f, 0.f, 0.f, 0.f};                                \
  STAGEH(Ag, sm);                                                             \
  STAGEH(Ag + 128 * DD, sm + 8192);                                           \
  STAGEH(Bg, sm + 32768);                                                     \
  STAGEH(Bg + 128 * DD, sm + 32768 + 8192);                                   \
  STAGEH(Ag + 64, sm + 16384);                                                \
  STAGEH(Ag + 128 * DD + 64, sm + 16384 + 8192);                              \
  asm volatile("s_waitcnt vmcnt(4)" ::: "memory");                            \
  __builtin_amdgcn_s_barrier();                                               \
  short8 a0[4][2], a1[4][2], bb[2][2];                                        \
  for (int u = 0; u < 8; ++u) {                                               \
    const int slot = u & 1;                                                   \
    const unsigned short* aS = aB + slot * 16384;                             \
    const unsigned short* bS = bB + slot * 16384;                             \
    const unsigned short* An = Ag + (u + 2) * 64;                             \
    const unsigned short* Bn = Bg + (u + 1) * 64;                             \
    unsigned short* sAd = sm + slot * 16384;                                  \
    unsigned short* sBd = sm + 32768 + (slot ^ 1) * 16384;                    \
    READ_A(a0, aS, 0);                                                        \
    READ_B(bS, 0);                                                            \
    if (u < 7) STAGEH(Bn, sBd);                                               \
    PHASE_SYNC_PRE                                                            \
    MFMA16(a0, 0, 0)                                                          \
    PHASE_SYNC_POST                                                           \
    READ_A(a1, aS, 4);                                                        \
    if (u < 7) STAGEH(Bn + 128 * DD, sBd + 8192);                             \
    PHASE_SYNC_PRE                                                            \
    MFMA16(a1, 4, 0)                                                          \
    PHASE_SYNC_POST                                                           \
    READ_B(bS, 1);                                                            \
    if (u < 6) STAGEH(An, sAd);                                               \
    PHASE_SYNC_PRE                                                            \
    MFMA16(a0, 0, 2)                                                          \
    PHASE_SYNC_POST                                                           \
    if (u < 6) STAGEH(An + 128 * DD, sAd + 8192);                             \
    __builtin_amdgcn_s_barrier();                                             \
    asm volatile("s_waitcnt lgkmcnt(0)" ::: "memory");                        \
    __builtin_amdgcn_sched_barrier(0);                                        \
    MFMA16(a1, 4, 2)                                                          \
    __builtin_amdgcn_sched_barrier(0);                                        \
    if (u < 6) {                                                              \
      asm volatile("s_waitcnt vmcnt(4)" ::: "memory");                        \
    } else if (u == 6) {                                                      \
      asm volatile("s_waitcnt vmcnt(0)" ::: "memory");                        \
    }                                                                         \
    __builtin_amdgcn_s_barrier();                                             \
  }

// ---------- fused QKV GEMM (outputs q/k/v bf16 [b][l][d]) ----------
__global__ __launch_bounds__(512, 2) void qkv_mfma_8ph(
    const unsigned short* __restrict__ Wt, const unsigned short* __restrict__ Xt,
    unsigned short* __restrict__ qn, unsigned short* __restrict__ kn,
    unsigned short* __restrict__ vn) {
  extern __shared__ __align__(16) unsigned short sm[];
  const int b = blockIdx.z;
  const int m0 = blockIdx.y * 256;
  const int n0 = blockIdx.x * 256;
  const int tid = threadIdx.x;
  const unsigned short* Ag = Wt + (size_t)m0 * DD;
  const unsigned short* Bg = Xt + ((size_t)b * LL + n0) * DD;

  GEMM_8PH_CORE

  // epilogue: stage C [l(256)][d(256)] bf16 in LDS (XOR-swizzled 16B slots
  // within each 512B row), then fully-coalesced 16B stores.
  __syncthreads();
#pragma unroll
  for (int i = 0; i < 8; i++)
#pragma unroll
    for (int j = 0; j < 4; j++) {
      const int dloc = wm * 128 + i * 16 + lh * 4;
      const int lloc = wn * 64 + j * 16 + l15;
      ushort4 pk;
      pk.x = f2bf(acc[i][j][0]);
      pk.y = f2bf(acc[i][j][1]);
      pk.z = f2bf(acc[i][j][2]);
      pk.w = f2bf(acc[i][j][3]);
      *(ushort4*)((char*)sm + ((lloc * 512 + dloc * 2) ^ ((lloc & 7) << 4))) = pk;
    }
  __syncthreads();
  const int sector = m0 >> 9;
  unsigned short* outp = ((sector == 0) ? qn : (sector == 1) ? kn : vn) +
                         (size_t)b * LL * DD + (m0 & 511);
#pragma unroll
  for (int it = 0; it < 16; it++) {
    const int flat = it * 8192 + tid * 16;  // bytes
    const int lloc = flat >> 9;
    const int off = flat & 511;
    const short8 vdat =
        *(const short8*)((const char*)sm + lloc * 512 + (off ^ ((lloc & 7) << 4)));
    *(short8*)(outp + (size_t)(n0 + lloc) * DD + (off >> 1)) = vdat;
  }
}

// ---------- nodes GEMM, 8-phase 256x256: out[b][e][l] f32 + bias ----------
// grid (16, 2, BB) = 256 blocks (1/CU). Same ascending-K accumulation
// order as the old 2-phase kernel -> bit-identical sums. Direct stores:
// each instr writes 4x 64B-dense segments (same traffic as before).
__global__ __launch_bounds__(512, 2) void nodes_mfma_8ph(
    const unsigned short* __restrict__ Wt, const unsigned short* __restrict__ At,
    const float* __restrict__ bo, float* __restrict__ out) {
  extern __shared__ __align__(16) unsigned short sm[];
  const int b = blockIdx.z;
  const int m0 = blockIdx.y * 256;
  const int n0 = blockIdx.x * 256;
  const int tid = threadIdx.x;
  const unsigned short* Ag = Wt + (size_t)m0 * DD;
  const unsigned short* Bg = At + ((size_t)b * LL + n0) * DD;

  GEMM_8PH_CORE

  float* outp = out + (size_t)b * DD * LL;
  const int ebase = m0 + wm * 128;
  const int col0 = n0 + wn * 64 + l15;
#pragma unroll
  for (int i = 0; i < 8; i++) {
    const int e0r = ebase + i * 16 + lh * 4;
#pragma unroll
    for (int r = 0; r < 4; r++) {
      const float bv = bo[e0r + r];
      float* rowp = outp + (size_t)(e0r + r) * LL + col0;
#pragma unroll
      for (int j = 0; j < 4; j++) rowp[j * 16] = acc[i][j][r] + bv;
    }
  }
}

// ---------- relay token QKV (f32 GEMV), 4-way K-split ----------
// grid (8, BB), block 256
__global__ __launch_bounds__(256) void relay_qkv(
    const float* __restrict__ y, const float* __restrict__ Wq,
    const float* __restrict__ Wk, const float* __restrict__ Wv,
    float* __restrict__ qr, float* __restrict__ kr, float* __restrict__ vr) {
  const int b = blockIdx.y;
  const int d0 = blockIdx.x * 64;
  const int tid = threadIdx.x;
  const int dl = tid & 63, eg = tid >> 6;
  __shared__ float ys[DD];
  __shared__ float r3[3][4][64];
  for (int i = tid; i < DD; i += 256) ys[i] = y[b * DD + i];
  __syncthreads();
  float aq = 0.f, ak = 0.f, av = 0.f;
  const int e0 = eg * 128;
  for (int e = e0; e < e0 + 128; e++) {
    const float yv = ys[e];
    aq = fmaf(yv, Wq[(size_t)e * DD + d0 + dl], aq);
    ak = fmaf(yv, Wk[(size_t)e * DD + d0 + dl], ak);
    av = fmaf(yv, Wv[(size_t)e * DD + d0 + dl], av);
  }
  r3[0][eg][dl] = aq;
  r3[1][eg][dl] = ak;
  r3[2][eg][dl] = av;
  __syncthreads();
  if (tid < 192) {
    const int m = tid >> 6, d = tid & 63;
    const float s = r3[m][0][d] + r3[m][1][d] + r3[m][2][d] + r3[m][3][d];
    float* dst = (m == 0) ? qr : (m == 1) ? kr : vr;
    dst[b * DD + d0 + d] = s;
  }
}

// ---------- local window attention + fused relay partial ----------
// grid (LL/32, NH, BB), block 256; 8 lanes per (l,head) row.
__global__ __launch_bounds__(256) void local_attn_f(
    const unsigned short* __restrict__ qn, const unsigned short* __restrict__ kn,
    const unsigned short* __restrict__ vn, const float* __restrict__ kr,
    const float* __restrict__ vr, const float* __restrict__ qrg,
    unsigned short* __restrict__ att_t, float* __restrict__ part) {
  const int b = blockIdx.z, n = blockIdx.y;
  const int tid = threadIdx.x;
  const int li = tid >> 3, dl = tid & 7;
  const int l0 = blockIdx.x * 32;
  const int l = l0 + li;
  __shared__ float krs[HD], vrs[HD], qrs[HD];
  __shared__ __align__(16) char ksb[34 * 128];
  __shared__ __align__(16) char vsb[34 * 128];
  __shared__ float sv2[32];
  __shared__ float os[32][68];
  const int rb = b * DD + n * HD;
  if (tid < HD) {
    krs[tid] = kr[rb + tid];
    vrs[tid] = vr[rb + tid];
    qrs[tid] = qrg[rb + tid];
  }

  // stage rows gl = l0-1+s, s=0..33 (clamped; clamped rows are masked)
  {
    const int s1 = tid >> 3;  // 0..31
    const int gl1 = min(max(l0 - 1 + s1, 0), LL - 1);
    const size_t gb1 = ((size_t)b * LL + gl1) * DD + n * HD + dl * 8;
    const int so1 = s1 * 128 + dl * 16;
    *(short8*)(ksb + so1) = *(const short8*)(kn + gb1);
    *(short8*)(vsb + so1) = *(const short8*)(vn + gb1);
    if (tid < 16) {
      const int s2 = 32 + (tid >> 3);  // 32, 33
      const int gl2 = min(l0 - 1 + s2, LL - 1);
      const size_t gb2 = ((size_t)b * LL + gl2) * DD + n * HD + dl * 8;
      const int so2 = s2 * 128 + dl * 16;
      *(short8*)(ksb + so2) = *(const short8*)(kn + gb2);
      *(short8*)(vsb + so2) = *(const short8*)(vn + gb2);
    }
  }
  __syncthreads();

  const size_t rowbase = ((size_t)b * LL + l) * DD + n * HD + dl * 8;
  const bool has_m = (l > 0), has_p = (l < LL - 1);
  const int lo = dl * 16;

  const short8 q8 = *(const short8*)(qn + rowbase);
  const short8 km8 = *(const short8*)(ksb + (li + 0) * 128 + lo);
  const short8 k08 = *(const short8*)(ksb + (li + 1) * 128 + lo);
  const short8 kp8 = *(const short8*)(ksb + (li + 2) * 128 + lo);

  float s0 = 0.f, s1 = 0.f, s2 = 0.f, s3 = 0.f;
  float qf[8];
#pragma unroll
  for (int j = 0; j < 8; j++) {
    qf[j] = bf2f((unsigned short)q8[j]);
    s0 = fmaf(qf[j], bf2f((unsigned short)km8[j]), s0);
    s1 = fmaf(qf[j], bf2f((unsigned short)k08[j]), s1);
    s2 = fmaf(qf[j], bf2f((unsigned short)kp8[j]), s2);
    s3 = fmaf(qf[j], krs[dl * 8 + j], s3);
  }
  s0 = grp8Sum(s0) * SCALE;
  s1 = grp8Sum(s1) * SCALE;
  s2 = grp8Sum(s2) * SCALE;
  s3 = grp8Sum(s3) * SCALE;
  // zero-padded boundary keys contribute score EXACTLY 0 inside the softmax
  if (!has_m) s0 = 0.f;
  if (!has_p) s2 = 0.f;
  const float m = fmaxf(fmaxf(s0, s1), fmaxf(s2, s3));
  const float e0 = __expf(s0 - m), e1 = __expf(s1 - m);
  const float e2 = __expf(s2 - m), e3 = __expf(s3 - m);
  const float inv = 1.f / (e0 + e1 + e2 + e3);
  const float a0 = has_m ? e0 * inv : 0.f;  // zero value vector at boundary
  const float a1 = e1 * inv;
  const float a2 = has_p ? e2 * inv : 0.f;
  const float a3 = e3 * inv;

  const short8 vm8 = *(const short8*)(vsb + (li + 0) * 128 + lo);
  const short8 v08 = *(const short8*)(vsb + (li + 1) * 128 + lo);
  const short8 vp8 = *(const short8*)(vsb + (li + 2) * 128 + lo);
  short8 o8;
#pragma unroll
  for (int j = 0; j < 8; j++) {
    float o = a0 * bf2f((unsigned short)vm8[j]) + a1 * bf2f((unsigned short)v08[j]) +
              a2 * bf2f((unsigned short)vp8[j]) + a3 * vrs[dl * 8 + j];
    o8[j] = (short)f2bf(o);
  }
  *(short8*)(att_t + rowbase) = o8;

  // ---- fused relay partial over rows l0..l0+31 (ksb/vsb rows 1..32) ----
  {
    const short8 kc = *(const short8*)(ksb + (li + 1) * 128 + lo);
    float p = 0.f;
#pragma unroll
    for (int j = 0; j < 8; j++) p = fmaf(qrs[dl * 8 + j], bf2f((unsigned short)kc[j]), p);
    p = grp8Sum(p);
    if (dl == 0) sv2[li] = p * SCALE;
  }
  __syncthreads();
  const int lane = tid & 63;
  const float sval = sv2[lane & 31];
  const float m2 = waveAllMax(sval);                                  // valid all lanes
  const float sum2 = waveAllSum((lane < 32) ? __expf(sval - m2) : 0.f);
  const float pp = __expf(sv2[li] - m2);
  {
    const short8 vc = *(const short8*)(vsb + (li + 1) * 128 + lo);
#pragma unroll
    for (int j = 0; j < 8; j++) os[li][dl * 8 + j] = pp * bf2f((unsigned short)vc[j]);
  }
  __syncthreads();
  float* po = part + (((size_t)b * NH + n) * NCH2 + blockIdx.x) * 68;
  if (tid < HD) {
    float t = 0.f;
#pragma unroll 8
    for (int g = 0; g < 32; g++) t += os[g][tid];
    po[tid] = t;
  }
  if (tid == 64) { po[64] = m2; po[65] = sum2; }
}

// ---------- fused relay combine + projection ----------
// grid (8, BB), block 256 (4 waves). Each block recomputes the tiny
// per-head combine (wave w -> heads w, w+4) into LDS (same fp order as
// the old combine kernel -> bit-identical), then does the 4-way K-split
// projection for its 64-e output chunk.
__global__ __launch_bounds__(256) void relay_proj_f(
    const float* __restrict__ qr, const float* __restrict__ krr,
    const float* __restrict__ vrr, const float* __restrict__ part,
    const float* __restrict__ Wstar, const float* __restrict__ bstar,
    float* __restrict__ out) {
  const int b = blockIdx.y;
  const int e0 = blockIdx.x * 64;
  const int tid = threadIdx.x;
  const int lane = tid & 63, w = tid >> 6;
  __shared__ float as[DD];
  __shared__ float r[4][64];
#pragma unroll
  for (int pass = 0; pass < 2; ++pass) {
    const int n = w + pass * 4;
    const int rb = b * DD + n * HD;
    float t = qr[rb + lane] * krr[rb + lane];
    t = waveSum(t);
    const float s_r = __shfl(t, 0, 64) * SCALE;
    const float* po = part + (((size_t)b * NH + n) * NCH2) * 68;
    float M = s_r;
#pragma unroll 8
    for (int c = 0; c < NCH2; c++) M = fmaxf(M, po[c * 68 + 64]);
    float S = __expf(s_r - M);
    float o = S * vrr[rb + lane];
#pragma unroll 4
    for (int c = 0; c < NCH2; c++) {
      const float e = __expf(po[c * 68 + 64] - M);
      S = fmaf(po[c * 68 + 65], e, S);
      o = fmaf(po[c * 68 + lane], e, o);
    }
    as[n * HD + lane] = o / S;
  }
  __syncthreads();
  const int el = tid & 63, dg = tid >> 6;
  float acc = 0.f;
  const int d0 = dg * 128;
  for (int d = d0; d < d0 + 128; d++)
    acc = fmaf(as[d], Wstar[(size_t)d * DD + e0 + el], acc);
  r[dg][el] = acc;
  __syncthreads();
  if (tid < 64)
    out[(size_t)BB * DD * LL + b * DD + e0 + tid] =
        r[0][tid] + r[1][tid] + r[2][tid] + r[3][tid] + bstar[e0 + tid];
}

extern "C" void kernel_launch(void* const* d_in, const int* in_sizes, int n_in,
                              void* d_out, int out_size, void* d_ws, size_t ws_size,
                              hipStream_t stream) {
  const float* x   = (const float*)d_in[0];
  const float* y   = (const float*)d_in[1];
  const float* Wq  = (const float*)d_in[2];
  const float* Wk  = (const float*)d_in[3];
  const float* Wv  = (const float*)d_in[4];
  const float* WOr = (const float*)d_in[5];
  const float* bOr = (const float*)d_in[6];
  const float* WOs = (const float*)d_in[7];
  const float* bOs = (const float*)d_in[8];
  float* out = (float*)d_out;

  char* ws = (char*)d_ws;
  const size_t SZ = (size_t)BB * DD * LL * sizeof(unsigned short);  // 32 MiB
  unsigned short* qn  = (unsigned short*)(ws);       // [b][l][d]
  unsigned short* kn  = (unsigned short*)(ws + SZ);  // [b][l][d]
  unsigned short* vn  = (unsigned short*)(ws + 2 * SZ);
  unsigned short* xt  = (unsigned short*)(ws + 3 * SZ);   // aliased: att_t after qkv
  unsigned short* att_t = xt;
  unsigned short* Wallt = (unsigned short*)(ws + 4 * SZ);              // 1536x512 bf16
  unsigned short* WOrt  = (unsigned short*)(ws + 4 * SZ + 1536 * 512 * 2);
  float* qr   = (float*)(ws + 4 * SZ + 2048 * 512 * 2);
  float* kr   = qr + BB * DD;
  float* vr   = kr + BB * DD;
  float* part = vr + BB * DD;   // BB*NH*NCH2*68 floats (~2.2 MB)

  static int smaxset = 0;
  if (!smaxset) {
    (void)hipFuncSetAttribute((const void*)qkv_mfma_8ph,
                              hipFuncAttributeMaxDynamicSharedMemorySize, 131072);
    (void)hipFuncSetAttribute((const void*)nodes_mfma_8ph,
                              hipFuncAttributeMaxDynamicSharedMemorySize, 131072);
    smaxset = 1;
  }

  prep_all<<<dim3(64, 8, BB + 1), 256, 0, stream>>>(
      x, xt, Wq, Wk, Wv, WOr,
      Wallt, Wallt + (size_t)512 * 512, Wallt + (size_t)1024 * 512, WOrt);

  qkv_mfma_8ph<<<dim3(16, 6, BB), 512, 131072, stream>>>(Wallt, xt, qn, kn, vn);
  relay_qkv<<<dim3(8, BB), 256, 0, stream>>>(y, Wq, Wk, Wv, qr, kr, vr);
  local_attn_f<<<dim3(LL / 32, NH, BB), 256, 0, stream>>>(qn, kn, vn, kr, vr, qr,
                                                          att_t, part);
  nodes_mfma_8ph<<<dim3(16, 2, BB), 512, 131072, stream>>>(WOrt, att_t, bOr, out);
  relay_proj_f<<<dim3(8, BB), 256, 0, stream>>>(qr, kr, vr, part, WOs, bOs, out);
}

// Round 7
// 262.901 us; speedup vs baseline: 1.2312x; 1.2312x over previous
//
#include <hip/hip_runtime.h>

#define BB 8
#define DD 512
#define LL 4096
#define NH 8
#define HD 64
#define SCALE 0.125f
#define NCH2 128

typedef __attribute__((ext_vector_type(8))) short short8;
typedef __attribute__((ext_vector_type(4))) float f32x4;

// ---------- bf16 helpers (bit-level, round-to-nearest-even) ----------
static __device__ __forceinline__ float bf2f(unsigned short u) {
  union { float f; unsigned int i; } c; c.i = ((unsigned int)u) << 16; return c.f;
}
static __device__ __forceinline__ unsigned short f2bf(float f) {
  union { float f; unsigned int i; } c; c.f = f;
  unsigned int i = c.i;
  unsigned int r = (i + 0x7fffu + ((i >> 16) & 1u)) >> 16;
  return (unsigned short)r;
}

// async global->LDS, 16B per lane; lds base must be wave-uniform
static __device__ __forceinline__ void gload_lds16(const void* g, void* l) {
  __builtin_amdgcn_global_load_lds(
      (const __attribute__((address_space(1))) void*)g,
      (__attribute__((address_space(3))) void*)l, 16, 0, 0);
}

// ---------- reductions ----------
static __device__ __forceinline__ float waveSum(float v) {
#pragma unroll
  for (int o = 32; o; o >>= 1) v += __shfl_down(v, o, 64);
  return v;
}
static __device__ __forceinline__ float grp8Sum(float v) {
  v += __shfl_xor(v, 1, 8);
  v += __shfl_xor(v, 2, 8);
  v += __shfl_xor(v, 4, 8);
  return v;
}
// butterfly variants: result valid in ALL lanes
static __device__ __forceinline__ float waveAllMax(float v) {
#pragma unroll
  for (int o = 1; o < 64; o <<= 1) v = fmaxf(v, __shfl_xor(v, o, 64));
  return v;
}
static __device__ __forceinline__ float waveAllSum(float v) {
#pragma unroll
  for (int o = 1; o < 64; o <<= 1) v += __shfl_xor(v, o, 64);
  return v;
}

// ---------- fused prep: X transpose (z<BB) + 4 weight transposes (z==BB) ----------
__global__ __launch_bounds__(256) void prep_all(
    const float* __restrict__ x, unsigned short* __restrict__ xt,
    const float* __restrict__ w0, const float* __restrict__ w1,
    const float* __restrict__ w2, const float* __restrict__ w3,
    unsigned short* __restrict__ o0, unsigned short* __restrict__ o1,
    unsigned short* __restrict__ o2, unsigned short* __restrict__ o3) {
  __shared__ float t[64][65];
  const int tid = threadIdx.x;
  const int r = tid >> 4;
  const int c4 = (tid & 15) * 4;
  if (blockIdx.z < BB) {
    const int b = blockIdx.z;
    const int e0 = blockIdx.y * 64;
    const int l0 = blockIdx.x * 64;
    const float* xb = x + (size_t)b * DD * LL;
#pragma unroll
    for (int p = 0; p < 4; p++) {
      const float4 v = *(const float4*)(xb + (size_t)(e0 + p * 16 + r) * LL + l0 + c4);
      *(float4*)&t[p * 16 + r][c4] = v;
    }
    __syncthreads();
#pragma unroll
    for (int p = 0; p < 4; p++) {
      const int ll = p * 16 + r;
      ushort4 o;
      o.x = f2bf(t[c4 + 0][ll]);
      o.y = f2bf(t[c4 + 1][ll]);
      o.z = f2bf(t[c4 + 2][ll]);
      o.w = f2bf(t[c4 + 3][ll]);
      *(ushort4*)(xt + ((size_t)b * LL + l0 + ll) * DD + e0 + c4) = o;
    }
  } else {
    const int wid = blockIdx.x + 64 * blockIdx.y;
    if (wid >= 256) return;
    const int s = wid >> 6;
    const int tb = wid & 63;
    const int m0 = (tb & 7) * 64;
    const int d0 = (tb >> 3) * 64;
    const float* win = (s == 0) ? w0 : (s == 1) ? w1 : (s == 2) ? w2 : w3;
    unsigned short* wout = (s == 0) ? o0 : (s == 1) ? o1 : (s == 2) ? o2 : o3;
#pragma unroll
    for (int p = 0; p < 4; p++) {
      const float4 v = *(const float4*)(win + (size_t)(d0 + p * 16 + r) * DD + m0 + c4);
      *(float4*)&t[p * 16 + r][c4] = v;
    }
    __syncthreads();
#pragma unroll
    for (int p = 0; p < 4; p++) {
      const int ll = p * 16 + r;
      ushort4 o;
      o.x = f2bf(t[c4 + 0][ll]);
      o.y = f2bf(t[c4 + 1][ll]);
      o.z = f2bf(t[c4 + 2][ll]);
      o.w = f2bf(t[c4 + 3][ll]);
      *(ushort4*)(wout + (size_t)(m0 + ll) * DD + d0 + c4) = o;
    }
  }
}

// ==================================================================
// 8-phase 256x256 MFMA GEMM core (T2+T3+T4+T5), verified R1/R4/R5.
// LINEAR block decode (R3: XCD swizzle regressed). R1 schedule (R2:
// deeper prefetch regressed). Shared by qkv and nodes kernels.
// ==================================================================
#define STAGEH(g, s)                                       \
  do {                                                     \
    gload_lds16((g) + sgoff, (s) + sloff);                 \
    gload_lds16((g) + sgoff + 32, (s) + sloff + 4096);     \
  } while (0)

#define READ_A(dst, base, ib)                                           \
  _Pragma("unroll") for (int i = 0; i < 4; i++) {                       \
    dst[i][0] = *(const short8*)((base) + ((ib) + i) * 512);            \
    dst[i][1] = *(const short8*)((base) + ((ib) + i) * 512 + 4096);     \
  }

#define READ_B(base, qn_)                                               \
  _Pragma("unroll") for (int j = 0; j < 2; j++) {                       \
    bb[j][0] = *(const short8*)((base) + (qn_) * 1024 + j * 512);       \
    bb[j][1] = *(const short8*)((base) + (qn_) * 1024 + j * 512 + 4096);\
  }

#define MFMA16(AF, IO, JO)                                                    \
  __builtin_amdgcn_s_setprio(1);                                              \
  _Pragma("unroll") for (int i = 0; i < 4; i++)                               \
  _Pragma("unroll") for (int j = 0; j < 2; j++) {                             \
    acc[(IO) + i][(JO) + j] = __builtin_amdgcn_mfma_f32_16x16x32_bf16(        \
        AF[i][0], bb[j][0], acc[(IO) + i][(JO) + j], 0, 0, 0);                \
    acc[(IO) + i][(JO) + j] = __builtin_amdgcn_mfma_f32_16x16x32_bf16(        \
        AF[i][1], bb[j][1], acc[(IO) + i][(JO) + j], 0, 0, 0);                \
  }                                                                           \
  __builtin_amdgcn_s_setprio(0);

#define PHASE_SYNC_PRE                                     \
  __builtin_amdgcn_s_barrier();                            \
  asm volatile("s_waitcnt lgkmcnt(0)" ::: "memory");       \
  __builtin_amdgcn_sched_barrier(0);

#define PHASE_SYNC_POST                                    \
  __builtin_amdgcn_sched_barrier(0);                       \
  __builtin_amdgcn_s_barrier();

// the shared K-loop body (prologue + 8 K-tiles); declares/fills acc[8][4]
#define GEMM_8PH_CORE                                                         \
  const int lane = tid & 63, w = tid >> 6;                                    \
  const int wm = w >> 2, wn = w & 3;                                          \
  const int l15 = lane & 15, lh = lane >> 4;                                  \
  const int kswz = (lh << 3) ^ ((l15 & 8) << 1);                              \
  const unsigned short* aB = sm + wm * 8192 + l15 * 32 + kswz;                \
  const unsigned short* bB = sm + 32768 + (wn >> 1) * 8192 +                  \
                             (wn & 1) * 2048 + l15 * 32 + kswz;               \
  const int srow = (w << 4) + (lane >> 2);                                    \
  const size_t sgoff = (size_t)srow * DD +                                    \
      ((size_t)(((lane & 3) << 3) ^ ((srow & 8) << 1)));                      \
  const int sloff = w * 512;                                                  \
  f32x4 acc[8][4];                                                            \
  _Pragma("unroll") for (int i = 0; i < 8; i++)                               \
  _Pragma("unroll") for (int j = 0; j < 4; j++)                               \
      acc[i][j] = (f32x4){0.f, 0.f, 0.f, 0.f};                                \
  STAGEH(Ag, sm);                                                             \
  STAGEH(Ag + 128 * DD, sm + 8192);                                           \
  STAGEH(Bg, sm + 32768);                                                     \
  STAGEH(Bg + 128 * DD, sm + 32768 + 8192);                                   \
  STAGEH(Ag + 64, sm + 16384);                                                \
  STAGEH(Ag + 128 * DD + 64, sm + 16384 + 8192);                              \
  asm volatile("s_waitcnt vmcnt(4)" ::: "memory");                            \
  __builtin_amdgcn_s_barrier();                                               \
  short8 a0[4][2], a1[4][2], bb[2][2];                                        \
  for (int u = 0; u < 8; ++u) {                                               \
    const int slot = u & 1;                                                   \
    const unsigned short* aS = aB + slot * 16384;                             \
    const unsigned short* bS = bB + slot * 16384;                             \
    const unsigned short* An = Ag + (u + 2) * 64;                             \
    const unsigned short* Bn = Bg + (u + 1) * 64;                             \
    unsigned short* sAd = sm + slot * 16384;                                  \
    unsigned short* sBd = sm + 32768 + (slot ^ 1) * 16384;                    \
    READ_A(a0, aS, 0);                                                        \
    READ_B(bS, 0);                                                            \
    if (u < 7) STAGEH(Bn, sBd);                                               \
    PHASE_SYNC_PRE                                                            \
    MFMA16(a0, 0, 0)                                                          \
    PHASE_SYNC_POST                                                           \
    READ_A(a1, aS, 4);                                                        \
    if (u < 7) STAGEH(Bn + 128 * DD, sBd + 8192);                             \
    PHASE_SYNC_PRE                                                            \
    MFMA16(a1, 4, 0)                                                          \
    PHASE_SYNC_POST                                                           \
    READ_B(bS, 1);                                                            \
    if (u < 6) STAGEH(An, sAd);                                               \
    PHASE_SYNC_PRE                                                            \
    MFMA16(a0, 0, 2)                                                          \
    PHASE_SYNC_POST                                                           \
    if (u < 6) STAGEH(An + 128 * DD, sAd + 8192);                             \
    __builtin_amdgcn_s_barrier();                                             \
    asm volatile("s_waitcnt lgkmcnt(0)" ::: "memory");                        \
    __builtin_amdgcn_sched_barrier(0);                                        \
    MFMA16(a1, 4, 2)                                                          \
    __builtin_amdgcn_sched_barrier(0);                                        \
    if (u < 6) {                                                              \
      asm volatile("s_waitcnt vmcnt(4)" ::: "memory");                        \
    } else if (u == 6) {                                                      \
      asm volatile("s_waitcnt vmcnt(0)" ::: "memory");                        \
    }                                                                         \
    __builtin_amdgcn_s_barrier();                                             \
  }

// ---------- fused QKV GEMM (outputs q/k/v bf16 [b][l][d]) ----------
__global__ __launch_bounds__(512, 2) void qkv_mfma_8ph(
    const unsigned short* __restrict__ Wt, const unsigned short* __restrict__ Xt,
    unsigned short* __restrict__ qn, unsigned short* __restrict__ kn,
    unsigned short* __restrict__ vn) {
  extern __shared__ __align__(16) unsigned short sm[];
  const int b = blockIdx.z;
  const int m0 = blockIdx.y * 256;
  const int n0 = blockIdx.x * 256;
  const int tid = threadIdx.x;
  const unsigned short* Ag = Wt + (size_t)m0 * DD;
  const unsigned short* Bg = Xt + ((size_t)b * LL + n0) * DD;

  GEMM_8PH_CORE

  // epilogue: stage C [l(256)][d(256)] bf16 in LDS (XOR-swizzled 16B slots
  // within each 512B row), then fully-coalesced 16B stores.
  __syncthreads();
#pragma unroll
  for (int i = 0; i < 8; i++)
#pragma unroll
    for (int j = 0; j < 4; j++) {
      const int dloc = wm * 128 + i * 16 + lh * 4;
      const int lloc = wn * 64 + j * 16 + l15;
      ushort4 pk;
      pk.x = f2bf(acc[i][j][0]);
      pk.y = f2bf(acc[i][j][1]);
      pk.z = f2bf(acc[i][j][2]);
      pk.w = f2bf(acc[i][j][3]);
      *(ushort4*)((char*)sm + ((lloc * 512 + dloc * 2) ^ ((lloc & 7) << 4))) = pk;
    }
  __syncthreads();
  const int sector = m0 >> 9;
  unsigned short* outp = ((sector == 0) ? qn : (sector == 1) ? kn : vn) +
                         (size_t)b * LL * DD + (m0 & 511);
#pragma unroll
  for (int it = 0; it < 16; it++) {
    const int flat = it * 8192 + tid * 16;  // bytes
    const int lloc = flat >> 9;
    const int off = flat & 511;
    const short8 vdat =
        *(const short8*)((const char*)sm + lloc * 512 + (off ^ ((lloc & 7) << 4)));
    *(short8*)(outp + (size_t)(n0 + lloc) * DD + (off >> 1)) = vdat;
  }
}

// ---------- nodes GEMM, 8-phase 256x256: out[b][e][l] f32 + bias ----------
__global__ __launch_bounds__(512, 2) void nodes_mfma_8ph(
    const unsigned short* __restrict__ Wt, const unsigned short* __restrict__ At,
    const float* __restrict__ bo, float* __restrict__ out) {
  extern __shared__ __align__(16) unsigned short sm[];
  const int b = blockIdx.z;
  const int m0 = blockIdx.y * 256;
  const int n0 = blockIdx.x * 256;
  const int tid = threadIdx.x;
  const unsigned short* Ag = Wt + (size_t)m0 * DD;
  const unsigned short* Bg = At + ((size_t)b * LL + n0) * DD;

  GEMM_8PH_CORE

  float* outp = out + (size_t)b * DD * LL;
  const int ebase = m0 + wm * 128;
  const int col0 = n0 + wn * 64 + l15;
#pragma unroll
  for (int i = 0; i < 8; i++) {
    const int e0r = ebase + i * 16 + lh * 4;
#pragma unroll
    for (int r = 0; r < 4; r++) {
      const float bv = bo[e0r + r];
      float* rowp = outp + (size_t)(e0r + r) * LL + col0;
#pragma unroll
      for (int j = 0; j < 4; j++) rowp[j * 16] = acc[i][j][r] + bv;
    }
  }
}

// ---------- relay token QKV (f32 GEMV), 4-way K-split ----------
// grid (8, BB), block 256
__global__ __launch_bounds__(256) void relay_qkv(
    const float* __restrict__ y, const float* __restrict__ Wq,
    const float* __restrict__ Wk, const float* __restrict__ Wv,
    float* __restrict__ qr, float* __restrict__ kr, float* __restrict__ vr) {
  const int b = blockIdx.y;
  const int d0 = blockIdx.x * 64;
  const int tid = threadIdx.x;
  const int dl = tid & 63, eg = tid >> 6;
  __shared__ float ys[DD];
  __shared__ float r3[3][4][64];
  for (int i = tid; i < DD; i += 256) ys[i] = y[b * DD + i];
  __syncthreads();
  float aq = 0.f, ak = 0.f, av = 0.f;
  const int e0 = eg * 128;
  for (int e = e0; e < e0 + 128; e++) {
    const float yv = ys[e];
    aq = fmaf(yv, Wq[(size_t)e * DD + d0 + dl], aq);
    ak = fmaf(yv, Wk[(size_t)e * DD + d0 + dl], ak);
    av = fmaf(yv, Wv[(size_t)e * DD + d0 + dl], av);
  }
  r3[0][eg][dl] = aq;
  r3[1][eg][dl] = ak;
  r3[2][eg][dl] = av;
  __syncthreads();
  if (tid < 192) {
    const int m = tid >> 6, d = tid & 63;
    const float s = r3[m][0][d] + r3[m][1][d] + r3[m][2][d] + r3[m][3][d];
    float* dst = (m == 0) ? qr : (m == 1) ? kr : vr;
    dst[b * DD + d0 + d] = s;
  }
}

// ---------- local window attention + fused relay partial ----------
// grid (LL/32, NH, BB), block 256; 8 lanes per (l,head) row.
__global__ __launch_bounds__(256) void local_attn_f(
    const unsigned short* __restrict__ qn, const unsigned short* __restrict__ kn,
    const unsigned short* __restrict__ vn, const float* __restrict__ kr,
    const float* __restrict__ vr, const float* __restrict__ qrg,
    unsigned short* __restrict__ att_t, float* __restrict__ part) {
  const int b = blockIdx.z, n = blockIdx.y;
  const int tid = threadIdx.x;
  const int li = tid >> 3, dl = tid & 7;
  const int l0 = blockIdx.x * 32;
  const int l = l0 + li;
  __shared__ float krs[HD], vrs[HD], qrs[HD];
  __shared__ __align__(16) char ksb[34 * 128];
  __shared__ __align__(16) char vsb[34 * 128];
  __shared__ float sv2[32];
  __shared__ float os[32][68];
  const int rb = b * DD + n * HD;
  if (tid < HD) {
    krs[tid] = kr[rb + tid];
    vrs[tid] = vr[rb + tid];
    qrs[tid] = qrg[rb + tid];
  }

  // stage rows gl = l0-1+s, s=0..33 (clamped; clamped rows are masked)
  {
    const int s1 = tid >> 3;  // 0..31
    const int gl1 = min(max(l0 - 1 + s1, 0), LL - 1);
    const size_t gb1 = ((size_t)b * LL + gl1) * DD + n * HD + dl * 8;
    const int so1 = s1 * 128 + dl * 16;
    *(short8*)(ksb + so1) = *(const short8*)(kn + gb1);
    *(short8*)(vsb + so1) = *(const short8*)(vn + gb1);
    if (tid < 16) {
      const int s2 = 32 + (tid >> 3);  // 32, 33
      const int gl2 = min(l0 - 1 + s2, LL - 1);
      const size_t gb2 = ((size_t)b * LL + gl2) * DD + n * HD + dl * 8;
      const int so2 = s2 * 128 + dl * 16;
      *(short8*)(ksb + so2) = *(const short8*)(kn + gb2);
      *(short8*)(vsb + so2) = *(const short8*)(vn + gb2);
    }
  }
  __syncthreads();

  const size_t rowbase = ((size_t)b * LL + l) * DD + n * HD + dl * 8;
  const bool has_m = (l > 0), has_p = (l < LL - 1);
  const int lo = dl * 16;

  const short8 q8 = *(const short8*)(qn + rowbase);
  const short8 km8 = *(const short8*)(ksb + (li + 0) * 128 + lo);
  const short8 k08 = *(const short8*)(ksb + (li + 1) * 128 + lo);
  const short8 kp8 = *(const short8*)(ksb + (li + 2) * 128 + lo);

  float s0 = 0.f, s1 = 0.f, s2 = 0.f, s3 = 0.f;
  float qf[8];
#pragma unroll
  for (int j = 0; j < 8; j++) {
    qf[j] = bf2f((unsigned short)q8[j]);
    s0 = fmaf(qf[j], bf2f((unsigned short)km8[j]), s0);
    s1 = fmaf(qf[j], bf2f((unsigned short)k08[j]), s1);
    s2 = fmaf(qf[j], bf2f((unsigned short)kp8[j]), s2);
    s3 = fmaf(qf[j], krs[dl * 8 + j], s3);
  }
  s0 = grp8Sum(s0) * SCALE;
  s1 = grp8Sum(s1) * SCALE;
  s2 = grp8Sum(s2) * SCALE;
  s3 = grp8Sum(s3) * SCALE;
  // zero-padded boundary keys contribute score EXACTLY 0 inside the softmax
  if (!has_m) s0 = 0.f;
  if (!has_p) s2 = 0.f;
  const float m = fmaxf(fmaxf(s0, s1), fmaxf(s2, s3));
  const float e0 = __expf(s0 - m), e1 = __expf(s1 - m);
  const float e2 = __expf(s2 - m), e3 = __expf(s3 - m);
  const float inv = 1.f / (e0 + e1 + e2 + e3);
  const float a0 = has_m ? e0 * inv : 0.f;  // zero value vector at boundary
  const float a1 = e1 * inv;
  const float a2 = has_p ? e2 * inv : 0.f;
  const float a3 = e3 * inv;

  const short8 vm8 = *(const short8*)(vsb + (li + 0) * 128 + lo);
  const short8 v08 = *(const short8*)(vsb + (li + 1) * 128 + lo);
  const short8 vp8 = *(const short8*)(vsb + (li + 2) * 128 + lo);
  short8 o8;
#pragma unroll
  for (int j = 0; j < 8; j++) {
    float o = a0 * bf2f((unsigned short)vm8[j]) + a1 * bf2f((unsigned short)v08[j]) +
              a2 * bf2f((unsigned short)vp8[j]) + a3 * vrs[dl * 8 + j];
    o8[j] = (short)f2bf(o);
  }
  *(short8*)(att_t + rowbase) = o8;

  // ---- fused relay partial over rows l0..l0+31 (ksb/vsb rows 1..32) ----
  {
    const short8 kc = *(const short8*)(ksb + (li + 1) * 128 + lo);
    float p = 0.f;
#pragma unroll
    for (int j = 0; j < 8; j++) p = fmaf(qrs[dl * 8 + j], bf2f((unsigned short)kc[j]), p);
    p = grp8Sum(p);
    if (dl == 0) sv2[li] = p * SCALE;
  }
  __syncthreads();
  const int lane = tid & 63;
  const float sval = sv2[lane & 31];
  const float m2 = waveAllMax(sval);                                  // valid all lanes
  const float sum2 = waveAllSum((lane < 32) ? __expf(sval - m2) : 0.f);
  const float pp = __expf(sv2[li] - m2);
  {
    const short8 vc = *(const short8*)(vsb + (li + 1) * 128 + lo);
#pragma unroll
    for (int j = 0; j < 8; j++) os[li][dl * 8 + j] = pp * bf2f((unsigned short)vc[j]);
  }
  __syncthreads();
  float* po = part + (((size_t)b * NH + n) * NCH2 + blockIdx.x) * 68;
  if (tid < HD) {
    float t = 0.f;
#pragma unroll 8
    for (int g = 0; g < 32; g++) t += os[g][tid];
    po[tid] = t;
  }
  if (tid == 64) { po[64] = m2; po[65] = sum2; }
}

// ---------- relay combine, PARALLEL over chunks ----------
// grid (NH, BB), block 256. R6's serial 128-chunk loop was a 77.8us
// latency chain (124 GB/s, 1.9% VALU). Parallel form: threads 0..127
// load all (m,sum) pairs at once; block-reduce M and S; o[h] summed by
// (h, chunk-group) threads with coalesced po reads; computed ONCE per
// (b,n) (R6 recomputed it 8x).
__global__ __launch_bounds__(256) void relay_combine_par(
    const float* __restrict__ qr, const float* __restrict__ krr,
    const float* __restrict__ vrr, const float* __restrict__ part,
    float* __restrict__ attr) {
  const int n = blockIdx.x, b = blockIdx.y;
  const int tid = threadIdx.x;
  const int rb = b * DD + n * HD;
  __shared__ float lw[NCH2];
  __shared__ float red[8];
  __shared__ float o4[4][64];
  __shared__ float srs;
  const float* po = part + (((size_t)b * NH + n) * NCH2) * 68;

  float mloc = -1e30f;
  if (tid < NCH2) mloc = po[tid * 68 + 64];
  if (tid < 64) {  // wave 0 entire: relay-token score
    float t = qr[rb + tid] * krr[rb + tid];
    t = waveAllSum(t);
    if (tid == 0) srs = t * SCALE;
  }
  const float wm_ = waveAllMax(mloc);
  if ((tid & 63) == 0) red[tid >> 6] = wm_;
  __syncthreads();
  const float M = fmaxf(fmaxf(fmaxf(red[0], red[1]), fmaxf(red[2], red[3])), srs);
  float spart = 0.f;
  if (tid < NCH2) {
    const float e = __expf(mloc - M);
    lw[tid] = e;
    spart = po[tid * 68 + 65] * e;
  }
  const float ws_ = waveAllSum(spart);
  if ((tid & 63) == 0) red[4 + (tid >> 6)] = ws_;
  __syncthreads();
  const float er = __expf(srs - M);
  const float S = er + red[4] + red[5] + red[6] + red[7];
  // o[h]: thread (h=tid&63, g=tid>>6) sums chunks [g*32, g*32+32)
  const int h = tid & 63, g = tid >> 6;
  float o = 0.f;
#pragma unroll 8
  for (int c = g * 32; c < g * 32 + 32; c++) o = fmaf(lw[c], po[c * 68 + h], o);
  o4[g][h] = o;
  __syncthreads();
  if (tid < 64) {
    const float oo =
        o4[0][tid] + o4[1][tid] + o4[2][tid] + o4[3][tid] + er * vrr[rb + tid];
    attr[rb + tid] = oo / S;
  }
}

// ---------- relay projection, 4-way K-split (R5-verified form) ----------
// grid (8, BB), block 256
__global__ __launch_bounds__(256) void relay_proj(
    const float* __restrict__ attr, const float* __restrict__ Wstar,
    const float* __restrict__ bstar, float* __restrict__ out) {
  const int b = blockIdx.y;
  const int e0 = blockIdx.x * 64;
  const int tid = threadIdx.x;
  const int el = tid & 63, dg = tid >> 6;
  __shared__ float as[DD];
  __shared__ float r[4][64];
  for (int i = tid; i < DD; i += 256) as[i] = attr[b * DD + i];
  __syncthreads();
  float acc = 0.f;
  const int d0 = dg * 128;
  for (int d = d0; d < d0 + 128; d++)
    acc = fmaf(as[d], Wstar[(size_t)d * DD + e0 + el], acc);
  r[dg][el] = acc;
  __syncthreads();
  if (tid < 64)
    out[(size_t)BB * DD * LL + b * DD + e0 + tid] =
        r[0][tid] + r[1][tid] + r[2][tid] + r[3][tid] + bstar[e0 + tid];
}

extern "C" void kernel_launch(void* const* d_in, const int* in_sizes, int n_in,
                              void* d_out, int out_size, void* d_ws, size_t ws_size,
                              hipStream_t stream) {
  const float* x   = (const float*)d_in[0];
  const float* y   = (const float*)d_in[1];
  const float* Wq  = (const float*)d_in[2];
  const float* Wk  = (const float*)d_in[3];
  const float* Wv  = (const float*)d_in[4];
  const float* WOr = (const float*)d_in[5];
  const float* bOr = (const float*)d_in[6];
  const float* WOs = (const float*)d_in[7];
  const float* bOs = (const float*)d_in[8];
  float* out = (float*)d_out;

  char* ws = (char*)d_ws;
  const size_t SZ = (size_t)BB * DD * LL * sizeof(unsigned short);  // 32 MiB
  unsigned short* qn  = (unsigned short*)(ws);       // [b][l][d]
  unsigned short* kn  = (unsigned short*)(ws + SZ);  // [b][l][d]
  unsigned short* vn  = (unsigned short*)(ws + 2 * SZ);
  unsigned short* xt  = (unsigned short*)(ws + 3 * SZ);   // aliased: att_t after qkv
  unsigned short* att_t = xt;
  unsigned short* Wallt = (unsigned short*)(ws + 4 * SZ);              // 1536x512 bf16
  unsigned short* WOrt  = (unsigned short*)(ws + 4 * SZ + 1536 * 512 * 2);
  float* qr   = (float*)(ws + 4 * SZ + 2048 * 512 * 2);
  float* kr   = qr + BB * DD;
  float* vr   = kr + BB * DD;
  float* attr = vr + BB * DD;
  float* part = attr + BB * DD;   // BB*NH*NCH2*68 floats (~2.2 MB)

  static int smaxset = 0;
  if (!smaxset) {
    (void)hipFuncSetAttribute((const void*)qkv_mfma_8ph,
                              hipFuncAttributeMaxDynamicSharedMemorySize, 131072);
    (void)hipFuncSetAttribute((const void*)nodes_mfma_8ph,
                              hipFuncAttributeMaxDynamicSharedMemorySize, 131072);
    smaxset = 1;
  }

  prep_all<<<dim3(64, 8, BB + 1), 256, 0, stream>>>(
      x, xt, Wq, Wk, Wv, WOr,
      Wallt, Wallt + (size_t)512 * 512, Wallt + (size_t)1024 * 512, WOrt);

  qkv_mfma_8ph<<<dim3(16, 6, BB), 512, 131072, stream>>>(Wallt, xt, qn, kn, vn);
  relay_qkv<<<dim3(8, BB), 256, 0, stream>>>(y, Wq, Wk, Wv, qr, kr, vr);
  local_attn_f<<<dim3(LL / 32, NH, BB), 256, 0, stream>>>(qn, kn, vn, kr, vr, qr,
                                                          att_t, part);
  nodes_mfma_8ph<<<dim3(16, 2, BB), 512, 131072, stream>>>(WOrt, att_t, bOr, out);
  relay_combine_par<<<dim3(NH, BB), 256, 0, stream>>>(qr, kr, vr, part, attr);
  relay_proj<<<dim3(8, BB), 256, 0, stream>>>(attr, WOs, bOs, out);
}